// Round 13
// baseline (628.327 us; speedup 1.0000x reference)
//
#include <hip/hip_runtime.h>
#include <hip/hip_bf16.h>

#define BB 64
#define TT 512
#define FF 1024
#define KK 64

typedef unsigned char uchar;

// ---------------- Emission GEMM (round-1 version, measured ~83-88us, 6x) ----------------
#define BM 64
#define BF 64
#define LDA 68

__global__ __launch_bounds__(256)
void emission_kernel(const float* __restrict__ X, const float* __restrict__ W,
                     const float* __restrict__ bias, float* __restrict__ em)
{
    __shared__ float As[BF][LDA];
    __shared__ float Bs[BF][LDA];
    const int tid = threadIdx.x;
    const int row0 = blockIdx.x * BM;
    const int tm = tid & 15;
    const int tn = tid >> 4;
    const int lq = tid & 15;
    const int lr = tid >> 4;

    float acc[4][4];
#pragma unroll
    for (int i = 0; i < 4; ++i)
#pragma unroll
        for (int jj = 0; jj < 4; ++jj) acc[i][jj] = 0.f;

    for (int f0 = 0; f0 < FF; f0 += BF) {
#pragma unroll
        for (int p = 0; p < 4; ++p) {
            const int r = p * 16 + lr;
            float4 a = *(const float4*)(X + (size_t)(row0 + r) * FF + f0 + lq * 4);
            As[lq * 4 + 0][r] = a.x;
            As[lq * 4 + 1][r] = a.y;
            As[lq * 4 + 2][r] = a.z;
            As[lq * 4 + 3][r] = a.w;
            float4 w = *(const float4*)(W + (size_t)r * FF + f0 + lq * 4);
            Bs[lq * 4 + 0][r] = w.x;
            Bs[lq * 4 + 1][r] = w.y;
            Bs[lq * 4 + 2][r] = w.z;
            Bs[lq * 4 + 3][r] = w.w;
        }
        __syncthreads();
#pragma unroll
        for (int f = 0; f < BF; ++f) {
            float4 a = *(const float4*)&As[f][tm * 4];
            float4 b = *(const float4*)&Bs[f][tn * 4];
            acc[0][0] += a.x * b.x; acc[0][1] += a.x * b.y; acc[0][2] += a.x * b.z; acc[0][3] += a.x * b.w;
            acc[1][0] += a.y * b.x; acc[1][1] += a.y * b.y; acc[1][2] += a.y * b.z; acc[1][3] += a.y * b.w;
            acc[2][0] += a.z * b.x; acc[2][1] += a.z * b.y; acc[2][2] += a.z * b.z; acc[2][3] += a.z * b.w;
            acc[3][0] += a.w * b.x; acc[3][1] += a.w * b.y; acc[3][2] += a.w * b.z; acc[3][3] += a.w * b.w;
        }
        __syncthreads();
    }

    const float4 b4 = *(const float4*)(bias + tn * 4);
#pragma unroll
    for (int i = 0; i < 4; ++i) {
        float4 o;
        o.x = acc[i][0] + b4.x;
        o.y = acc[i][1] + b4.y;
        o.z = acc[i][2] + b4.z;
        o.w = acc[i][3] + b4.w;
        *(float4*)(em + (size_t)(row0 + tm * 4 + i) * KK + tn * 4) = o;
    }
}

// ---------------- Forward: value-only recurrence, TWO sequences per wave ----------------
// r12 post-mortem: bpermute broadcast regressed (LDS-pipe lgkmcnt serialization);
// readlane is the better broadcast. r10-r12 model: ~4.7 cy/instr from
// readlane->add producer-consumer stalls with no independent work to fill them.
// Fix: interleave TWO independent recurrences (2 seqs/wave) -> the scheduler
// slots seq-B ops into seq-A's stall cycles. tc shared+pinned (r11-proven).
#define RL(S, I) __uint_as_float((unsigned)__builtin_amdgcn_readlane((int)__float_as_uint(S), (I)))

// 8-candidate chunk max for score S, chunk c -> w_
#define CHUNK8(S, C, W_) do {                                                  \
    const float v0 = RL(S, (C) * 8 + 0) + tc[(C) * 8 + 0];                     \
    const float v1 = RL(S, (C) * 8 + 1) + tc[(C) * 8 + 1];                     \
    const float v2 = RL(S, (C) * 8 + 2) + tc[(C) * 8 + 2];                     \
    const float v3 = RL(S, (C) * 8 + 3) + tc[(C) * 8 + 3];                     \
    const float v4 = RL(S, (C) * 8 + 4) + tc[(C) * 8 + 4];                     \
    const float v5 = RL(S, (C) * 8 + 5) + tc[(C) * 8 + 5];                     \
    const float v6 = RL(S, (C) * 8 + 6) + tc[(C) * 8 + 6];                     \
    const float v7 = RL(S, (C) * 8 + 7) + tc[(C) * 8 + 7];                     \
    const float ma = fmaxf(fmaxf(v0, v1), v2);                                 \
    const float mb = fmaxf(fmaxf(v3, v4), v5);                                 \
    const float mc = fmaxf(fmaxf(v6, v7), ma);                                 \
    W_ = fmaxf(mb, mc);                                                        \
} while (0)

#define VSTEP1(S, EV, SB, TIDX) do {                                           \
    float m_;                                                                  \
    _Pragma("unroll")                                                          \
    for (int c = 0; c < 8; ++c) {                                              \
        float w_;                                                              \
        CHUNK8(S, c, w_);                                                      \
        m_ = (c == 0) ? w_ : fmaxf(m_, w_);                                    \
    }                                                                          \
    S = m_ + (EV);                                                             \
    SB[(size_t)(TIDX) * KK + j] = S;                                           \
} while (0)

// both sequences, interleaved chunk-by-chunk (independent chains fill stalls)
#define VSTEP2(TIDX) do {                                                      \
    float m0_, m1_;                                                            \
    _Pragma("unroll")                                                          \
    for (int c = 0; c < 8; ++c) {                                              \
        float w0_, w1_;                                                        \
        CHUNK8(s0, c, w0_);                                                    \
        CHUNK8(s1, c, w1_);                                                    \
        m0_ = (c == 0) ? w0_ : fmaxf(m0_, w0_);                                \
        m1_ = (c == 0) ? w1_ : fmaxf(m1_, w1_);                                \
    }                                                                          \
    s0 = m0_ + eC0;                                                            \
    s1 = m1_ + eC1;                                                            \
    sb0[(size_t)(TIDX) * KK + j] = s0;                                         \
    sb1[(size_t)(TIDX) * KK + j] = s1;                                         \
} while (0)

__global__ __launch_bounds__(64)
__attribute__((amdgpu_waves_per_eu(1, 1)))
void viterbi_fwd(const float* __restrict__ em, const void* __restrict__ maskp,
                 const float* __restrict__ startT, const float* __restrict__ endT,
                 const float* __restrict__ trans, float* __restrict__ shist,
                 int* __restrict__ btarr)
{
    const int bp = blockIdx.x;          // pair id 0..31
    const int b0 = bp * 2, b1 = bp * 2 + 1;
    const int j = threadIdx.x;

    const uchar* m8 = (const uchar*)maskp;
    const int* m32 = (const int*)maskp;
    const bool u8m = (m8[1] != 0);

    // ---- length precompute for both sequences (mask monotone) ----
    int c0, c1;
    if (u8m) {
        const uint2 v0 = *(const uint2*)(m8 + (size_t)b0 * TT + j * 8);
        const uint2 v1 = *(const uint2*)(m8 + (size_t)b1 * TT + j * 8);
        c0 = (int)((((v0.x & 0x01010101u) + (v0.y & 0x01010101u)) * 0x01010101u) >> 24);
        c1 = (int)((((v1.x & 0x01010101u) + (v1.y & 0x01010101u)) * 0x01010101u) >> 24);
    } else {
        const int* p0 = m32 + (size_t)b0 * TT + j * 8;
        const int* p1 = m32 + (size_t)b1 * TT + j * 8;
        const int4 a0 = *(const int4*)p0, d0 = *(const int4*)(p0 + 4);
        const int4 a1 = *(const int4*)p1, d1 = *(const int4*)(p1 + 4);
        c0 = (a0.x != 0) + (a0.y != 0) + (a0.z != 0) + (a0.w != 0)
           + (d0.x != 0) + (d0.y != 0) + (d0.z != 0) + (d0.w != 0);
        c1 = (a1.x != 0) + (a1.y != 0) + (a1.z != 0) + (a1.w != 0)
           + (d1.x != 0) + (d1.y != 0) + (d1.z != 0) + (d1.w != 0);
    }
#pragma unroll
    for (int o = 1; o < 64; o <<= 1) { c0 += __shfl_xor(c0, o, 64); c1 += __shfl_xor(c1, o, 64); }
    const int len0 = c0, len1 = c1;
    const int lenm = (len0 > len1) ? len0 : len1;

    float tc[KK];
#pragma unroll
    for (int i = 0; i < KK; ++i) tc[i] = trans[i * KK + j];
#pragma unroll
    for (int i = 0; i < KK; ++i) asm volatile("" : "+v"(tc[i]));

    const float* e0 = em + (size_t)b0 * TT * KK;
    const float* e1 = em + (size_t)b1 * TT * KK;
    float* sb0 = shist + (size_t)b0 * TT * KK;
    float* sb1 = shist + (size_t)b1 * TT * KK;

    const float st = startT[j];
    float s0 = st + e0[j];  sb0[j] = s0;
    float s1 = st + e1[j];  sb1[j] = s1;

    float eC0 = e0[KK + j];
    float eC1 = e1[KK + j];

    for (int t = 1; t < lenm; ++t) {
        const int tn = (t + 1 < TT) ? (t + 1) : (TT - 1);
        const float eN0 = e0[(size_t)tn * KK + j];
        const float eN1 = e1[(size_t)tn * KK + j];

        const bool a0 = (t < len0), a1 = (t < len1);   // wave-uniform
        if (a0 & a1) {
            VSTEP2(t);
        } else if (a0) {
            VSTEP1(s0, eC0, sb0, t);
        } else {
            VSTEP1(s1, eC1, sb1, t);
        }
        eC0 = eN0; eC1 = eN1;
    }

    const float ev = endT[j];
    s0 += ev; s1 += ev;
    // one-time first-index argmax over lanes for each sequence
    float bm0 = -__builtin_inff(), bm1 = -__builtin_inff();
    int bt0 = 0, bt1 = 0;
#pragma unroll
    for (int i = 0; i < KK; ++i) {
        const float x0 = RL(s0, i);
        const float x1 = RL(s1, i);
        if (x0 > bm0) { bm0 = x0; bt0 = i; }
        if (x1 > bm1) { bm1 = x1; bt1 = i; }
    }
    if (j == 0) { btarr[b0] = bt0; btarr[b1] = bt1; }
}

// ---------------- hist recompute: massively parallel (validated r8-r12) ----------------
__global__ __launch_bounds__(256)
void hist_kernel(const float* __restrict__ em, const void* __restrict__ maskp,
                 const float* __restrict__ trans, const float* __restrict__ shist,
                 uchar* __restrict__ histg)
{
    const int tid = threadIdx.x;
    const int bid = blockIdx.x;
    const int b = bid >> 6;
    const int t0 = (bid & 63) * 8;

    __shared__ float tl[64][65];
    __shared__ float srow[8][64];

    const uchar* m8 = (const uchar*)maskp;
    const int* m32 = (const int*)maskp;
    const bool u8m = (m8[1] != 0);

#pragma unroll
    for (int p = 0; p < 16; ++p) {
        const int idx = p * 256 + tid;
        tl[idx >> 6][idx & 63] = trans[idx];
    }
#pragma unroll
    for (int p = 0; p < 2; ++p) {
        const int idx = p * 256 + tid;
        const int r = idx >> 6, i2 = idx & 63;
        const int ts = t0 - 1 + r;
        srow[r][i2] = (ts >= 0) ? shist[((size_t)b * TT + ts) * KK + i2] : 0.f;
    }
    __syncthreads();

    const int j = tid & 63;
    const int tq = tid >> 6;

#pragma unroll
    for (int half = 0; half < 2; ++half) {
        const int toff = tq * 2 + half;
        const int t = t0 + toff;
        if (t == 0) continue;
        const int mt = u8m ? (int)m8[b * TT + t] : m32[b * TT + t];
        uchar hv;
        if (!mt) {
            hv = (uchar)j;
        } else {
            const float e = em[((size_t)b * TT + t) * KK + j];
            const float* sr = &srow[toff][0];
            float bm = -__builtin_inff();
            int bi = 0;
#pragma unroll 16
            for (int i = 0; i < KK; ++i) {
                const float cand = (sr[i] + tl[i][j]) + e;   // reference order
                if (cand > bm) { bm = cand; bi = i; }        // strict >: first index
            }
            hv = (uchar)bi;
        }
        histg[((size_t)b * TT + t) * KK + j] = hv;
    }
}

// ---------------- Backtrack (validated r8-r12) ----------------
__global__ __launch_bounds__(256)
void viterbi_bt(const uchar* __restrict__ histg, const int* __restrict__ btarr,
                float* __restrict__ pred)
{
    const int b = blockIdx.x;
    const int tid = threadIdx.x;
    const int w = tid >> 6;
    const int j = tid & 63;

    __shared__ uchar hist[TT][KK];
    __shared__ uchar hypo[8][64][64];

    const uint4* src = (const uint4*)(histg + (size_t)b * TT * KK);
    uint4* dst = (uint4*)&hist[0][0];
#pragma unroll
    for (int p = 0; p < 8; ++p) dst[p * 256 + tid] = src[p * 256 + tid];
    __syncthreads();

    const int bt = btarr[b];

#pragma unroll
    for (int ss = 0; ss < 2; ++ss) {
        const int s = w * 2 + ss;
        int tag = j;
        if (s == 7) {
            hypo[7][63][j] = (uchar)j;
            for (int t = TT - 1; t >= 7 * 64 + 1; --t) {
                tag = hist[t][tag];
                hypo[7][t - 1 - 7 * 64][j] = (uchar)tag;
            }
        } else {
            for (int t = (s + 1) * 64; t >= s * 64 + 1; --t) {
                tag = hist[t][tag];
                hypo[s][t - 1 - s * 64][j] = (uchar)tag;
            }
        }
    }
    __syncthreads();

    int rows_[8];
    rows_[7] = bt;
#pragma unroll
    for (int s = 6; s >= 0; --s) rows_[s] = hypo[s + 1][0][rows_[s + 1]];

    float* pb = pred + (size_t)b * TT;
#pragma unroll
    for (int ss = 0; ss < 2; ++ss) {
        const int s = w * 2 + ss;
        pb[s * 64 + j] = (float)hypo[s][j][rows_[s]];
    }
}

// ---------------- Fallback monolithic viterbi (round-6, proven) ----------------
__global__ __launch_bounds__(256)
void viterbi_kernel(const float* __restrict__ em, const void* __restrict__ maskp,
                    const float* __restrict__ startT, const float* __restrict__ endT,
                    const float* __restrict__ trans, float* __restrict__ pred)
{
    const int b = blockIdx.x;
    const int tid = threadIdx.x;
    const int w = tid >> 6;
    const int j = tid & 63;

    __shared__ uchar hist[TT][KK];
    __shared__ uchar hypo[8][64][64];
    __shared__ int bt_sh;

    const uchar* m8 = (const uchar*)maskp;
    const int* m32 = (const int*)maskp;
    const bool u8m = (m8[1] != 0);

    if (w == 0) {
        float tc[KK];
#pragma unroll
        for (int i = 0; i < KK; ++i) tc[i] = trans[i * KK + j];

        const float* emb = em + (size_t)b * TT * KK;
        float score = startT[j] + emb[j];
        const float endv = endT[j];

        float e_cur = emb[KK + j];
        int   m_cur = u8m ? (int)m8[b * TT + 1] : m32[b * TT + 1];

        int t = 1;
        for (; t < TT; ++t) {
            const int tn2 = (t + 1 < TT) ? (t + 1) : (TT - 1);
            const float e_next = emb[(size_t)tn2 * KK + j];
            const int   m_next = u8m ? (int)m8[b * TT + tn2] : m32[b * TT + tn2];
            if (!m_cur) break;
            float m = -__builtin_inff();
            int idx = 0;
#pragma unroll
            for (int i = 0; i < KK; ++i) {
                const float si = __uint_as_float(__builtin_amdgcn_readlane(__float_as_uint(score), i));
                const float v = (si + tc[i]) + e_cur;
                if (v > m) { m = v; idx = i; }
            }
            score = m;
            hist[t][j] = (uchar)idx;
            e_cur = e_next; m_cur = m_next;
        }
        for (; t < TT; ++t) hist[t][j] = (uchar)j;

        score += endv;
        float bm = -__builtin_inff();
        int bt = 0;
#pragma unroll
        for (int i = 0; i < KK; ++i) {
            const float si = __uint_as_float(__builtin_amdgcn_readlane(__float_as_uint(score), i));
            if (si > bm) { bm = si; bt = i; }
        }
        if (j == 0) bt_sh = bt;
    }
    __syncthreads();

#pragma unroll
    for (int ss = 0; ss < 2; ++ss) {
        const int s = w * 2 + ss;
        int tag = j;
        if (s == 7) {
            hypo[7][63][j] = (uchar)j;
            for (int t = TT - 1; t >= 7 * 64 + 1; --t) {
                tag = hist[t][tag];
                hypo[7][t - 1 - 7 * 64][j] = (uchar)tag;
            }
        } else {
            for (int t = (s + 1) * 64; t >= s * 64 + 1; --t) {
                tag = hist[t][tag];
                hypo[s][t - 1 - s * 64][j] = (uchar)tag;
            }
        }
    }
    __syncthreads();

    const int bt = bt_sh;
    int rows_[8];
    rows_[7] = bt;
#pragma unroll
    for (int s = 6; s >= 0; --s) rows_[s] = hypo[s + 1][0][rows_[s + 1]];

    float* pb = pred + (size_t)b * TT;
#pragma unroll
    for (int ss = 0; ss < 2; ++ss) {
        const int s = w * 2 + ss;
        pb[s * 64 + j] = (float)hypo[s][j][rows_[s]];
    }
}

extern "C" void kernel_launch(void* const* d_in, const int* in_sizes, int n_in,
                              void* d_out, int out_size, void* d_ws, size_t ws_size,
                              hipStream_t stream) {
    const float* X      = (const float*)d_in[0];
    const void*  mask   = d_in[1];
    const float* W      = (const float*)d_in[2];
    const float* bias   = (const float*)d_in[3];
    const float* startT = (const float*)d_in[4];
    const float* endT   = (const float*)d_in[5];
    const float* trans  = (const float*)d_in[6];

    float* em   = (float*)d_out;
    float* pred = (float*)d_out + (size_t)BB * TT * KK;

    emission_kernel<<<(BB * TT) / BM, 256, 0, stream>>>(X, W, bias, em);

    const size_t SH_BYTES = (size_t)BB * TT * KK * sizeof(float);   // 8 MB
    const size_t HI_BYTES = (size_t)BB * TT * KK;                   // 2 MB
    const size_t NEED = SH_BYTES + HI_BYTES + 256;

    if (ws_size >= NEED) {
        float* shist = (float*)d_ws;
        uchar* histg = (uchar*)d_ws + SH_BYTES;
        int*   btarr = (int*)((uchar*)d_ws + SH_BYTES + HI_BYTES);
        viterbi_fwd<<<BB / 2, 64, 0, stream>>>(em, mask, startT, endT, trans, shist, btarr);
        hist_kernel<<<BB * 64, 256, 0, stream>>>(em, mask, trans, shist, histg);
        viterbi_bt<<<BB, 256, 0, stream>>>(histg, btarr, pred);
    } else {
        viterbi_kernel<<<BB, 256, 0, stream>>>(em, mask, startT, endT, trans, pred);
    }
}

// Round 14
// 273.535 us; speedup vs baseline: 2.2971x; 2.2971x over previous
//
#include <hip/hip_runtime.h>
#include <hip/hip_bf16.h>

#define BB 64
#define TT 512
#define FF 1024
#define KK 64

typedef unsigned char uchar;

// ---------------- Emission GEMM (round-1 version, measured ~83-88us, 6x) ----------------
#define BM 64
#define BF 64
#define LDA 68

__global__ __launch_bounds__(256)
void emission_kernel(const float* __restrict__ X, const float* __restrict__ W,
                     const float* __restrict__ bias, float* __restrict__ em)
{
    __shared__ float As[BF][LDA];
    __shared__ float Bs[BF][LDA];
    const int tid = threadIdx.x;
    const int row0 = blockIdx.x * BM;
    const int tm = tid & 15;
    const int tn = tid >> 4;
    const int lq = tid & 15;
    const int lr = tid >> 4;

    float acc[4][4];
#pragma unroll
    for (int i = 0; i < 4; ++i)
#pragma unroll
        for (int jj = 0; jj < 4; ++jj) acc[i][jj] = 0.f;

    for (int f0 = 0; f0 < FF; f0 += BF) {
#pragma unroll
        for (int p = 0; p < 4; ++p) {
            const int r = p * 16 + lr;
            float4 a = *(const float4*)(X + (size_t)(row0 + r) * FF + f0 + lq * 4);
            As[lq * 4 + 0][r] = a.x;
            As[lq * 4 + 1][r] = a.y;
            As[lq * 4 + 2][r] = a.z;
            As[lq * 4 + 3][r] = a.w;
            float4 w = *(const float4*)(W + (size_t)r * FF + f0 + lq * 4);
            Bs[lq * 4 + 0][r] = w.x;
            Bs[lq * 4 + 1][r] = w.y;
            Bs[lq * 4 + 2][r] = w.z;
            Bs[lq * 4 + 3][r] = w.w;
        }
        __syncthreads();
#pragma unroll
        for (int f = 0; f < BF; ++f) {
            float4 a = *(const float4*)&As[f][tm * 4];
            float4 b = *(const float4*)&Bs[f][tn * 4];
            acc[0][0] += a.x * b.x; acc[0][1] += a.x * b.y; acc[0][2] += a.x * b.z; acc[0][3] += a.x * b.w;
            acc[1][0] += a.y * b.x; acc[1][1] += a.y * b.y; acc[1][2] += a.y * b.z; acc[1][3] += a.y * b.w;
            acc[2][0] += a.z * b.x; acc[2][1] += a.z * b.y; acc[2][2] += a.z * b.z; acc[2][3] += a.z * b.w;
            acc[3][0] += a.w * b.x; acc[3][1] += a.w * b.y; acc[3][2] += a.w * b.z; acc[3][3] += a.w * b.w;
        }
        __syncthreads();
    }

    const float4 b4 = *(const float4*)(bias + tn * 4);
#pragma unroll
    for (int i = 0; i < 4; ++i) {
        float4 o;
        o.x = acc[i][0] + b4.x;
        o.y = acc[i][1] + b4.y;
        o.z = acc[i][2] + b4.z;
        o.w = acc[i][3] + b4.w;
        *(float4*)(em + (size_t)(row0 + tm * 4 + i) * KK + tn * 4) = o;
    }
}

// ---------------- Forward: value-only recurrence, 1 wave/seq ----------------
// r13 post-mortem: the wall is the VALU-writes-SGPR -> VALU-reads-SGPR hazard
// fired on EVERY readlane->add pair (compiler emits them adjacent). Fix:
// batch 8 readlanes in ONE asm block with 8 distinct "=s" outputs -> every
// dependent add is >=8 instructions downstream of its SGPR write -> 0 hazards.
#define CHUNKA(B) do {                                                         \
    float r0, r1, r2, r3, r4, r5, r6, r7;                                      \
    asm("v_readlane_b32 %0, %8, %9\n\t"                                        \
        "v_readlane_b32 %1, %8, %10\n\t"                                       \
        "v_readlane_b32 %2, %8, %11\n\t"                                       \
        "v_readlane_b32 %3, %8, %12\n\t"                                       \
        "v_readlane_b32 %4, %8, %13\n\t"                                       \
        "v_readlane_b32 %5, %8, %14\n\t"                                       \
        "v_readlane_b32 %6, %8, %15\n\t"                                       \
        "v_readlane_b32 %7, %8, %16\n\t"                                       \
        : "=s"(r0), "=s"(r1), "=s"(r2), "=s"(r3),                              \
          "=s"(r4), "=s"(r5), "=s"(r6), "=s"(r7)                               \
        : "v"(score),                                                          \
          "i"((B) + 0), "i"((B) + 1), "i"((B) + 2), "i"((B) + 3),              \
          "i"((B) + 4), "i"((B) + 5), "i"((B) + 6), "i"((B) + 7));             \
    const float v0 = r0 + tc[(B) + 0];                                         \
    const float v1 = r1 + tc[(B) + 1];                                         \
    const float v2 = r2 + tc[(B) + 2];                                         \
    const float v3 = r3 + tc[(B) + 3];                                         \
    const float v4 = r4 + tc[(B) + 4];                                         \
    const float v5 = r5 + tc[(B) + 5];                                         \
    const float v6 = r6 + tc[(B) + 6];                                         \
    const float v7 = r7 + tc[(B) + 7];                                         \
    const float ma = fmaxf(fmaxf(v0, v1), v2);   /* v_max3 */                  \
    const float mb = fmaxf(fmaxf(v3, v4), v5);                                 \
    const float mc = fmaxf(fmaxf(v6, v7), ma);                                 \
    const float w_ = fmaxf(mb, mc);                                            \
    m_ = ((B) == 0) ? w_ : fmaxf(m_, w_);                                      \
} while (0)

#define VSTEP(EV, TIDX) do {                                                   \
    float m_;                                                                  \
    CHUNKA(0);  CHUNKA(8);  CHUNKA(16); CHUNKA(24);                            \
    CHUNKA(32); CHUNKA(40); CHUNKA(48); CHUNKA(56);                            \
    score = m_ + (EV);                                                         \
    sb[(size_t)(TIDX) * KK + j] = score;                                       \
} while (0)

#define RLANE(I) __uint_as_float((unsigned)__builtin_amdgcn_readlane((int)__float_as_uint(score), (I)))

__global__ __launch_bounds__(64)
__attribute__((amdgpu_waves_per_eu(1, 1)))
void viterbi_fwd(const float* __restrict__ em, const void* __restrict__ maskp,
                 const float* __restrict__ startT, const float* __restrict__ endT,
                 const float* __restrict__ trans, float* __restrict__ shist,
                 int* __restrict__ btarr)
{
    const int b = blockIdx.x;
    const int j = threadIdx.x;

    const uchar* m8 = (const uchar*)maskp;
    const int* m32 = (const int*)maskp;
    const bool u8m = (m8[1] != 0);

    // ---- length precompute (mask is monotone: true for t < len) ----
    int myc;
    if (u8m) {
        const uint2 mv = *(const uint2*)(m8 + (size_t)b * TT + j * 8);
        const unsigned s4 = (mv.x & 0x01010101u) + (mv.y & 0x01010101u);
        myc = (int)((s4 * 0x01010101u) >> 24);
    } else {
        const int* mp = m32 + (size_t)b * TT + j * 8;
        const int4 a = *(const int4*)mp;
        const int4 c = *(const int4*)(mp + 4);
        myc = (a.x != 0) + (a.y != 0) + (a.z != 0) + (a.w != 0)
            + (c.x != 0) + (c.y != 0) + (c.z != 0) + (c.w != 0);
    }
#pragma unroll
    for (int o = 1; o < 64; o <<= 1) myc += __shfl_xor(myc, o, 64);
    const int len = myc;   // valid timesteps; loop runs t = 1..len-1

    float tc[KK];
#pragma unroll
    for (int i = 0; i < KK; ++i) tc[i] = trans[i * KK + j];
#pragma unroll
    for (int i = 0; i < KK; ++i) asm volatile("" : "+v"(tc[i]));

    const float* emb = em + (size_t)b * TT * KK;
    float* sb = shist + (size_t)b * TT * KK;

    float score = startT[j] + emb[j];   // t = 0
    sb[j] = score;

    // named prefetch slots: eA..eD hold e for t, t+1, t+2, t+3
    float eA = emb[1 * KK + j];
    float eB = emb[2 * KK + j];
    float eC = emb[3 * KK + j];
    float eD = emb[4 * KK + j];

    int t = 1;
    for (; t + 3 < len; t += 4) {
        VSTEP(eA, t);     eA = emb[(size_t)((t + 4 < TT) ? t + 4 : TT - 1) * KK + j];
        VSTEP(eB, t + 1); eB = emb[(size_t)((t + 5 < TT) ? t + 5 : TT - 1) * KK + j];
        VSTEP(eC, t + 2); eC = emb[(size_t)((t + 6 < TT) ? t + 6 : TT - 1) * KK + j];
        VSTEP(eD, t + 3); eD = emb[(size_t)((t + 7 < TT) ? t + 7 : TT - 1) * KK + j];
    }
    for (; t < len; ++t) {   // tail 0-3 steps
        VSTEP(eA, t);
        eA = eB; eB = eC; eC = eD;
    }

    score += endT[j];
    // one-time first-index argmax over lanes
    float bm = -__builtin_inff();
    int bt = 0;
#pragma unroll
    for (int i = 0; i < KK; ++i) {
        const float si = RLANE(i);
        if (si > bm) { bm = si; bt = i; }
    }
    if (j == 0) btarr[b] = bt;
}

// ---------------- hist recompute: massively parallel (validated r8-r13) ----------------
__global__ __launch_bounds__(256)
void hist_kernel(const float* __restrict__ em, const void* __restrict__ maskp,
                 const float* __restrict__ trans, const float* __restrict__ shist,
                 uchar* __restrict__ histg)
{
    const int tid = threadIdx.x;
    const int bid = blockIdx.x;
    const int b = bid >> 6;
    const int t0 = (bid & 63) * 8;

    __shared__ float tl[64][65];
    __shared__ float srow[8][64];

    const uchar* m8 = (const uchar*)maskp;
    const int* m32 = (const int*)maskp;
    const bool u8m = (m8[1] != 0);

#pragma unroll
    for (int p = 0; p < 16; ++p) {
        const int idx = p * 256 + tid;
        tl[idx >> 6][idx & 63] = trans[idx];
    }
#pragma unroll
    for (int p = 0; p < 2; ++p) {
        const int idx = p * 256 + tid;
        const int r = idx >> 6, i2 = idx & 63;
        const int ts = t0 - 1 + r;
        srow[r][i2] = (ts >= 0) ? shist[((size_t)b * TT + ts) * KK + i2] : 0.f;
    }
    __syncthreads();

    const int j = tid & 63;
    const int tq = tid >> 6;

#pragma unroll
    for (int half = 0; half < 2; ++half) {
        const int toff = tq * 2 + half;
        const int t = t0 + toff;
        if (t == 0) continue;
        const int mt = u8m ? (int)m8[b * TT + t] : m32[b * TT + t];
        uchar hv;
        if (!mt) {
            hv = (uchar)j;
        } else {
            const float e = em[((size_t)b * TT + t) * KK + j];
            const float* sr = &srow[toff][0];
            float bm = -__builtin_inff();
            int bi = 0;
#pragma unroll 16
            for (int i = 0; i < KK; ++i) {
                const float cand = (sr[i] + tl[i][j]) + e;   // reference order
                if (cand > bm) { bm = cand; bi = i; }        // strict >: first index
            }
            hv = (uchar)bi;
        }
        histg[((size_t)b * TT + t) * KK + j] = hv;
    }
}

// ---------------- Backtrack (validated r8-r13) ----------------
__global__ __launch_bounds__(256)
void viterbi_bt(const uchar* __restrict__ histg, const int* __restrict__ btarr,
                float* __restrict__ pred)
{
    const int b = blockIdx.x;
    const int tid = threadIdx.x;
    const int w = tid >> 6;
    const int j = tid & 63;

    __shared__ uchar hist[TT][KK];
    __shared__ uchar hypo[8][64][64];

    const uint4* src = (const uint4*)(histg + (size_t)b * TT * KK);
    uint4* dst = (uint4*)&hist[0][0];
#pragma unroll
    for (int p = 0; p < 8; ++p) dst[p * 256 + tid] = src[p * 256 + tid];
    __syncthreads();

    const int bt = btarr[b];

#pragma unroll
    for (int ss = 0; ss < 2; ++ss) {
        const int s = w * 2 + ss;
        int tag = j;
        if (s == 7) {
            hypo[7][63][j] = (uchar)j;
            for (int t = TT - 1; t >= 7 * 64 + 1; --t) {
                tag = hist[t][tag];
                hypo[7][t - 1 - 7 * 64][j] = (uchar)tag;
            }
        } else {
            for (int t = (s + 1) * 64; t >= s * 64 + 1; --t) {
                tag = hist[t][tag];
                hypo[s][t - 1 - s * 64][j] = (uchar)tag;
            }
        }
    }
    __syncthreads();

    int rows_[8];
    rows_[7] = bt;
#pragma unroll
    for (int s = 6; s >= 0; --s) rows_[s] = hypo[s + 1][0][rows_[s + 1]];

    float* pb = pred + (size_t)b * TT;
#pragma unroll
    for (int ss = 0; ss < 2; ++ss) {
        const int s = w * 2 + ss;
        pb[s * 64 + j] = (float)hypo[s][j][rows_[s]];
    }
}

// ---------------- Fallback monolithic viterbi (round-6, proven) ----------------
__global__ __launch_bounds__(256)
void viterbi_kernel(const float* __restrict__ em, const void* __restrict__ maskp,
                    const float* __restrict__ startT, const float* __restrict__ endT,
                    const float* __restrict__ trans, float* __restrict__ pred)
{
    const int b = blockIdx.x;
    const int tid = threadIdx.x;
    const int w = tid >> 6;
    const int j = tid & 63;

    __shared__ uchar hist[TT][KK];
    __shared__ uchar hypo[8][64][64];
    __shared__ int bt_sh;

    const uchar* m8 = (const uchar*)maskp;
    const int* m32 = (const int*)maskp;
    const bool u8m = (m8[1] != 0);

    if (w == 0) {
        float tc[KK];
#pragma unroll
        for (int i = 0; i < KK; ++i) tc[i] = trans[i * KK + j];

        const float* emb = em + (size_t)b * TT * KK;
        float score = startT[j] + emb[j];
        const float endv = endT[j];

        float e_cur = emb[KK + j];
        int   m_cur = u8m ? (int)m8[b * TT + 1] : m32[b * TT + 1];

        int t = 1;
        for (; t < TT; ++t) {
            const int tn2 = (t + 1 < TT) ? (t + 1) : (TT - 1);
            const float e_next = emb[(size_t)tn2 * KK + j];
            const int   m_next = u8m ? (int)m8[b * TT + tn2] : m32[b * TT + tn2];
            if (!m_cur) break;
            float m = -__builtin_inff();
            int idx = 0;
#pragma unroll
            for (int i = 0; i < KK; ++i) {
                const float si = __uint_as_float(__builtin_amdgcn_readlane(__float_as_uint(score), i));
                const float v = (si + tc[i]) + e_cur;
                if (v > m) { m = v; idx = i; }
            }
            score = m;
            hist[t][j] = (uchar)idx;
            e_cur = e_next; m_cur = m_next;
        }
        for (; t < TT; ++t) hist[t][j] = (uchar)j;

        score += endv;
        float bm = -__builtin_inff();
        int bt = 0;
#pragma unroll
        for (int i = 0; i < KK; ++i) {
            const float si = __uint_as_float(__builtin_amdgcn_readlane(__float_as_uint(score), i));
            if (si > bm) { bm = si; bt = i; }
        }
        if (j == 0) bt_sh = bt;
    }
    __syncthreads();

#pragma unroll
    for (int ss = 0; ss < 2; ++ss) {
        const int s = w * 2 + ss;
        int tag = j;
        if (s == 7) {
            hypo[7][63][j] = (uchar)j;
            for (int t = TT - 1; t >= 7 * 64 + 1; --t) {
                tag = hist[t][tag];
                hypo[7][t - 1 - 7 * 64][j] = (uchar)tag;
            }
        } else {
            for (int t = (s + 1) * 64; t >= s * 64 + 1; --t) {
                tag = hist[t][tag];
                hypo[s][t - 1 - s * 64][j] = (uchar)tag;
            }
        }
    }
    __syncthreads();

    const int bt = bt_sh;
    int rows_[8];
    rows_[7] = bt;
#pragma unroll
    for (int s = 6; s >= 0; --s) rows_[s] = hypo[s + 1][0][rows_[s + 1]];

    float* pb = pred + (size_t)b * TT;
#pragma unroll
    for (int ss = 0; ss < 2; ++ss) {
        const int s = w * 2 + ss;
        pb[s * 64 + j] = (float)hypo[s][j][rows_[s]];
    }
}

extern "C" void kernel_launch(void* const* d_in, const int* in_sizes, int n_in,
                              void* d_out, int out_size, void* d_ws, size_t ws_size,
                              hipStream_t stream) {
    const float* X      = (const float*)d_in[0];
    const void*  mask   = d_in[1];
    const float* W      = (const float*)d_in[2];
    const float* bias   = (const float*)d_in[3];
    const float* startT = (const float*)d_in[4];
    const float* endT   = (const float*)d_in[5];
    const float* trans  = (const float*)d_in[6];

    float* em   = (float*)d_out;
    float* pred = (float*)d_out + (size_t)BB * TT * KK;

    emission_kernel<<<(BB * TT) / BM, 256, 0, stream>>>(X, W, bias, em);

    const size_t SH_BYTES = (size_t)BB * TT * KK * sizeof(float);   // 8 MB
    const size_t HI_BYTES = (size_t)BB * TT * KK;                   // 2 MB
    const size_t NEED = SH_BYTES + HI_BYTES + 256;

    if (ws_size >= NEED) {
        float* shist = (float*)d_ws;
        uchar* histg = (uchar*)d_ws + SH_BYTES;
        int*   btarr = (int*)((uchar*)d_ws + SH_BYTES + HI_BYTES);
        viterbi_fwd<<<BB, 64, 0, stream>>>(em, mask, startT, endT, trans, shist, btarr);
        hist_kernel<<<BB * 64, 256, 0, stream>>>(em, mask, trans, shist, histg);
        viterbi_bt<<<BB, 256, 0, stream>>>(histg, btarr, pred);
    } else {
        viterbi_kernel<<<BB, 256, 0, stream>>>(em, mask, startT, endT, trans, pred);
    }
}